// Round 10
// baseline (1111.870 us; speedup 1.0000x reference)
//
#include <hip/hip_runtime.h>
#include <cfloat>

#define B_  32
#define D_  256
#define N_  2048
#define K_  512
#define V_  6
#define DN_ (D_*N_)        // 524288
#define DK_ (D_*K_)        // 131072
#define QSZ (B_*D_*N_)     // 16777216
#define TOKSZ (B_*N_)      // 65536
#define TOK_OFF QSZ
#define LOSS_OFF (QSZ + V_*TOKSZ)
#define MARGIN 0.02f
#define FCAP 32768
#define TPB 32                   // tokens per block
#define NBLK (TOKSZ/TPB)         // 2048 blocks

typedef __attribute__((ext_vector_type(8))) short short8b;   // 8 bf16 (4 VGPR)
typedef __attribute__((ext_vector_type(4))) float f32x4;

__device__ __forceinline__ unsigned short f2bf(float x) {
  unsigned u = __float_as_uint(x);
  unsigned r = (u + 0x7fffu + ((u >> 16) & 1u)) >> 16;   // RNE
  return (unsigned short)r;
}
__device__ __forceinline__ float bf2f(unsigned short h) {
  return __uint_as_float(((unsigned)h) << 16);
}
__device__ __forceinline__ unsigned orderf(float f) {   // total order as unsigned
  unsigned u = __float_as_uint(f);
  return (u >> 31) ? ~u : (u | 0x80000000u);
}
__device__ __forceinline__ float unorderf(unsigned u) {
  return __uint_as_float((u & 0x80000000u) ? (u & 0x7fffffffu) : ~u);
}
__device__ __forceinline__ unsigned long long shfl_xor_u64(unsigned long long v, int m) {
  int lo = __shfl_xor((int)(unsigned)(v & 0xffffffffull), m, 64);
  int hi = __shfl_xor((int)(unsigned)(v >> 32), m, 64);
  return ((unsigned long long)(unsigned)hi << 32) | (unsigned)lo;
}

// ---- prep: transpose emb[v][d][k] -> Ef32[vk][d] + bf16 hi/lo packs ----
__global__ __launch_bounds__(256) void pack_kernel(const float* __restrict__ emb,
                                                   float* __restrict__ Ef32,
                                                   unsigned short* __restrict__ Ehi,
                                                   unsigned short* __restrict__ Elo) {
  __shared__ float T[64][68];
  const int tid = threadIdx.x;
  const int k0 = blockIdx.x * 64, d0 = blockIdx.y * 64, v = blockIdx.z;
  const float* src = emb + (size_t)v * DK_;
  const int r = tid >> 4, c4 = (tid & 15) * 4;
  #pragma unroll
  for (int i = 0; i < 4; ++i) {
    int d = d0 + r + i * 16;
    float4 x = *(const float4*)(src + (size_t)d * K_ + k0 + c4);
    *(float4*)&T[r + i * 16][c4] = x;
  }
  __syncthreads();
  #pragma unroll
  for (int i = 0; i < 4; ++i) {
    int k = k0 + r + i * 16;
    float4 wv;
    wv.x = T[c4 + 0][r + i * 16];
    wv.y = T[c4 + 1][r + i * 16];
    wv.z = T[c4 + 2][r + i * 16];
    wv.w = T[c4 + 3][r + i * 16];
    size_t o = ((size_t)v * K_ + k) * 256 + d0 + c4;
    *(float4*)(Ef32 + o) = wv;
    ushort4 hv, lv;
    hv.x = f2bf(wv.x); lv.x = f2bf(wv.x - bf2f(hv.x));
    hv.y = f2bf(wv.y); lv.y = f2bf(wv.y - bf2f(hv.y));
    hv.z = f2bf(wv.z); lv.z = f2bf(wv.z - bf2f(hv.z));
    hv.w = f2bf(wv.w); lv.w = f2bf(wv.w - bf2f(hv.w));
    *(ushort4*)(Ehi + o) = hv;
    *(ushort4*)(Elo + o) = lv;
  }
}

// ---- ||e||^2 in f32 and f64 ----
__global__ __launch_bounds__(256) void en2_kernel(const float* __restrict__ Ef32,
                                                  float* __restrict__ en2f,
                                                  double* __restrict__ en2d) {
  __shared__ double P[64][4];
  const int tid = threadIdx.x;
  const int k = blockIdx.x * 64 + (tid >> 2), q = tid & 3;
  const float* e = Ef32 + (size_t)k * 256 + q * 64;
  double s = 0.0;
  #pragma unroll 8
  for (int i = 0; i < 64; ++i) { double x = (double)e[i]; s = fma(x, x, s); }
  P[tid >> 2][q] = s;
  __syncthreads();
  if (tid < 64) {
    int k2 = blockIdx.x * 64 + tid;
    double t = (P[tid][0] + P[tid][1]) + (P[tid][2] + P[tid][3]);
    en2d[k2] = t;
    en2f[k2] = (float)t;
  }
}

// ---- fused all-6-layer RVQ: residual in LDS (hi/lo bf16) ----
// Occupancy design: total regs (VGPR+AGPR unified) must be <=128 for 16
// waves/CU (HW granule rounds 129..256 -> 256 -> 8 waves; round-9 measured
// exactly that at 164 regs). Two k-passes of 4 kt-tiles shrink acc to 32
// regs; running argmin (p/s, 24 regs) carries across passes in ascending-k
// order (exact first-index tie-break). All loops fully unrolled: any
// runtime index on acc/p/s -> scratch (round-8: 6.9 GB spill).
__global__ __launch_bounds__(256, 4) void rvq_fused(
    const float* __restrict__ inputs,
    const unsigned short* __restrict__ Ehi, const unsigned short* __restrict__ Elo,
    const float* __restrict__ Ef32, const float* __restrict__ en2f,
    float* __restrict__ tokens, float* __restrict__ lossPart,
    int* __restrict__ flagCnt, int* __restrict__ flagList)
{
  __shared__ unsigned short Ahi[8 * 1024];   // 16 KB  [c][g][tok][8]
  __shared__ unsigned short Alo[8 * 1024];   // 16 KB
  __shared__ unsigned long long wmin[4][TPB];// 1 KB
  __shared__ float wsec[4][TPB];             // 0.5 KB
  __shared__ int sIdx[TPB];
  __shared__ float wred[4];

  const int tid = threadIdx.x;
  const int lane = tid & 63, w = tid >> 6;
  const int l15 = lane & 15, lg = lane >> 4;
  const int gt0 = blockIdx.x * TPB;
  const int b = gt0 >> 11, n0 = gt0 & (N_ - 1);
  const int kb = w * 128;

  // ---- stage inputs once: thread (tok = tid&31, c = tid>>5); coalesced 128B
  {
    const int tok = tid & 31, c = tid >> 5;
    const float* src = inputs + (size_t)b * DN_ + n0 + tok;
    #pragma unroll
    for (int g = 0; g < 4; ++g) {
      short8b hv, lv;
      #pragma unroll
      for (int e = 0; e < 8; ++e) {
        float x = src[(size_t)(c * 32 + g * 8 + e) * N_];
        unsigned short h = f2bf(x);
        hv[e] = (short)h;
        lv[e] = (short)f2bf(x - bf2f(h));
      }
      *(short8b*)&Ahi[c * 1024 + g * 256 + tok * 8] = hv;
      *(short8b*)&Alo[c * 1024 + g * 256 + tok * 8] = lv;
    }
  }
  __syncthreads();

  for (int v = 0; v < V_; ++v) {
    const unsigned short* ehiL = Ehi + (size_t)v * DK_ + (size_t)(kb + l15) * 256 + lg * 8;
    const unsigned short* eloL = Elo + (size_t)v * DK_ + (size_t)(kb + l15) * 256 + lg * 8;
    const float* Ef32v = Ef32 + (size_t)v * DK_;

    unsigned long long p[2][4];
    float s[2][4];
    #pragma unroll
    for (int tt = 0; tt < 2; ++tt)
      #pragma unroll
      for (int r = 0; r < 4; ++r) { p[tt][r] = ~0ull; s[tt][r] = FLT_MAX; }

    // ---- two k-passes of 4 kt-tiles each; acc[2][4] = 32 regs
    #pragma unroll
    for (int h = 0; h < 2; ++h) {
      f32x4 acc[2][4];
      #pragma unroll
      for (int tt = 0; tt < 2; ++tt)
        #pragma unroll
        for (int ktl = 0; ktl < 4; ++ktl) acc[tt][ktl] = (f32x4){0.f, 0.f, 0.f, 0.f};

      #pragma unroll
      for (int c = 0; c < 8; ++c) {
        short8b ah0 = *(const short8b*)&Ahi[c * 1024 + lg * 256 + l15 * 8];
        short8b ah1 = *(const short8b*)&Ahi[c * 1024 + lg * 256 + (16 + l15) * 8];
        short8b al0 = *(const short8b*)&Alo[c * 1024 + lg * 256 + l15 * 8];
        short8b al1 = *(const short8b*)&Alo[c * 1024 + lg * 256 + (16 + l15) * 8];
        #pragma unroll
        for (int ktl = 0; ktl < 4; ++ktl) {
          const int kth = h * 4 + ktl;
          short8b bh = *(const short8b*)(ehiL + (size_t)kth * 4096 + c * 32);
          short8b bl = *(const short8b*)(eloL + (size_t)kth * 4096 + c * 32);
          acc[0][ktl] = __builtin_amdgcn_mfma_f32_16x16x32_bf16(ah0, bh, acc[0][ktl], 0, 0, 0);
          acc[0][ktl] = __builtin_amdgcn_mfma_f32_16x16x32_bf16(ah0, bl, acc[0][ktl], 0, 0, 0);
          acc[0][ktl] = __builtin_amdgcn_mfma_f32_16x16x32_bf16(al0, bh, acc[0][ktl], 0, 0, 0);
          acc[1][ktl] = __builtin_amdgcn_mfma_f32_16x16x32_bf16(ah1, bh, acc[1][ktl], 0, 0, 0);
          acc[1][ktl] = __builtin_amdgcn_mfma_f32_16x16x32_bf16(ah1, bl, acc[1][ktl], 0, 0, 0);
          acc[1][ktl] = __builtin_amdgcn_mfma_f32_16x16x32_bf16(al1, bh, acc[1][ktl], 0, 0, 0);
        }
      }

      // fold this pass's 4 kt-tiles into the running argmin (ascending k)
      #pragma unroll
      for (int ktl = 0; ktl < 4; ++ktl) {
        const int kth = h * 4 + ktl;
        const float en = en2f[v * K_ + kb + kth * 16 + l15];
        const unsigned kkey = (unsigned)(kb + kth * 16 + l15);
        #pragma unroll
        for (int tt = 0; tt < 2; ++tt)
          #pragma unroll
          for (int r = 0; r < 4; ++r) {
            float dv = en - 2.f * acc[tt][ktl][r];
            unsigned long long pk = ((unsigned long long)orderf(dv) << 32) | kkey;
            if (pk < p[tt][r]) {
              s[tt][r] = fminf(s[tt][r], unorderf((unsigned)(p[tt][r] >> 32)));
              p[tt][r] = pk;
            } else {
              s[tt][r] = fminf(s[tt][r], dv);
            }
          }
      }
    }

    // ---- cross-lane reduce per token (first-index tie-break)
    #pragma unroll
    for (int tt = 0; tt < 2; ++tt)
      #pragma unroll
      for (int r = 0; r < 4; ++r) {
        const int token = tt * 16 + lg * 4 + r;
        unsigned long long pp = p[tt][r];
        float ss = s[tt][r];
        #pragma unroll
        for (int m = 1; m <= 8; m <<= 1) {
          unsigned long long po = shfl_xor_u64(pp, m);
          float so = __shfl_xor(ss, m, 64);
          unsigned long long pmax = (po < pp) ? pp : po;
          ss = fminf(fminf(ss, so), unorderf((unsigned)(pmax >> 32)));
          pp = (po < pp) ? po : pp;
        }
        if (l15 == 0) { wmin[w][token] = pp; wsec[w][token] = ss; }
      }
    __syncthreads();
    if (tid < TPB) {
      unsigned long long pp = wmin[0][tid]; float ss = wsec[0][tid];
      #pragma unroll
      for (int w2 = 1; w2 < 4; ++w2) {
        unsigned long long po = wmin[w2][tid]; float so = wsec[w2][tid];
        unsigned long long pmax = (po < pp) ? pp : po;
        ss = fminf(fminf(ss, so), unorderf((unsigned)(pmax >> 32)));
        pp = (po < pp) ? po : pp;
      }
      int kwin = (int)(pp & 0xffffffffull);
      sIdx[tid] = kwin;
      tokens[(size_t)v * TOKSZ + gt0 + tid] = (float)kwin;
      float bd = unorderf((unsigned)(pp >> 32));
      if (ss - bd < MARGIN) {          // near-tie: defer to exact post-pass
        int pos = atomicAdd(flagCnt, 1);
        if (pos < FCAP) flagList[pos] = gt0 + tid;
      }
    }
    __syncthreads();

    // ---- residual update in LDS: rn = (hi+lo) - e, re-split; fused loss
    const int uj = tid & 31, q = tid >> 5;
    const int kw = sIdx[uj];
    const float* er = Ef32v + (size_t)kw * 256 + q * 32;
    float lacc = 0.f;
    #pragma unroll
    for (int g = 0; g < 4; ++g) {
      unsigned short* ph = &Ahi[q * 1024 + g * 256 + uj * 8];
      unsigned short* pl = &Alo[q * 1024 + g * 256 + uj * 8];
      short8b h8 = *(const short8b*)ph;
      short8b l8 = *(const short8b*)pl;
      float4 e0 = *(const float4*)(er + g * 8);
      float4 e1 = *(const float4*)(er + g * 8 + 4);
      float ee[8] = {e0.x, e0.y, e0.z, e0.w, e1.x, e1.y, e1.z, e1.w};
      short8b nh, nl;
      #pragma unroll
      for (int jj = 0; jj < 8; ++jj) {
        float rv = bf2f((unsigned short)h8[jj]) + bf2f((unsigned short)l8[jj]);
        float rn = rv - ee[jj];
        unsigned short hh = f2bf(rn);
        nh[jj] = (short)hh;
        nl[jj] = (short)f2bf(rn - bf2f(hh));
        lacc += rn * rn;
      }
      if (v < V_ - 1) {
        *(short8b*)ph = nh;
        *(short8b*)pl = nl;
      }
    }
    #pragma unroll
    for (int m = 32; m >= 1; m >>= 1) lacc += __shfl_xor(lacc, m, 64);
    if (lane == 0) wred[w] = lacc;
    __syncthreads();
    if (tid == 0)
      lossPart[(size_t)v * NBLK + blockIdx.x] = (wred[0] + wred[1]) + (wred[2] + wred[3]);
    __syncthreads();   // Ahi/Alo + wred stable before next layer
  }
}

// ---- exact f64 full-chain re-argmin for flagged tokens (post-pass) ----
__global__ __launch_bounds__(256) void chain_fixup(
    const float* __restrict__ inputs, const float* __restrict__ Ef32,
    const double* __restrict__ en2d, float* __restrict__ tokens,
    const int* __restrict__ flagList, const int* __restrict__ flagCnt)
{
  __shared__ double rD[256];
  __shared__ double sbd[256];
  __shared__ int sbk[256];
  const int tid = threadIdx.x;
  int cnt = flagCnt[0]; if (cnt > FCAP) cnt = FCAP;
  for (int i = blockIdx.x; i < cnt; i += gridDim.x) {
    const int gt = flagList[i];
    const int b = gt >> 11, n = gt & (N_ - 1);
    rD[tid] = (double)inputs[(size_t)b * DN_ + (size_t)tid * N_ + n];
    __syncthreads();
    for (int v = 0; v < V_; ++v) {
      const float* Ev = Ef32 + (size_t)v * DK_;
      double best = 1.0e300; int bk = 0;
      #pragma unroll
      for (int half = 0; half < 2; ++half) {
        const int k = tid + half * 256;
        const float* e0 = Ev + (size_t)k * 256;
        double s0 = 0.0, s1 = 0.0, s2 = 0.0, s3 = 0.0;
        #pragma unroll 8
        for (int dd = 0; dd < 256; dd += 4) {
          s0 = fma(rD[dd + 0], (double)e0[dd + 0], s0);
          s1 = fma(rD[dd + 1], (double)e0[dd + 1], s1);
          s2 = fma(rD[dd + 2], (double)e0[dd + 2], s2);
          s3 = fma(rD[dd + 3], (double)e0[dd + 3], s3);
        }
        double dist = en2d[v * K_ + k] - 2.0 * ((s0 + s1) + (s2 + s3));
        if (dist < best) { best = dist; bk = k; }   // k=tid before tid+256: keep lower
      }
      sbd[tid] = best; sbk[tid] = bk;
      __syncthreads();
      for (int st = 128; st >= 1; st >>= 1) {
        if (tid < st) {
          double od = sbd[tid + st]; int ok = sbk[tid + st];
          if (od < sbd[tid] || (od == sbd[tid] && ok < sbk[tid])) {
            sbd[tid] = od; sbk[tid] = ok;
          }
        }
        __syncthreads();
      }
      const int nk = sbk[0];
      if (tid == 0) tokens[(size_t)v * TOKSZ + gt] = (float)nk;
      double e = (double)Ev[(size_t)nk * 256 + tid];
      __syncthreads();
      rD[tid] = rD[tid] - e;
      __syncthreads();
    }
  }
}

// ---- q_sum[b][d][n] = sum_v Ef32[v][tok_v][d] ----
__global__ __launch_bounds__(256) void finalize_q(const float* __restrict__ toks,
                                                  const float* __restrict__ Ef32,
                                                  float* __restrict__ out) {
  const int tid = threadIdx.x;
  const int gt = blockIdx.x * 64 + (tid >> 2);
  const int q = tid & 3;
  const int b = gt >> 11, n = gt & (N_ - 1);
  float4 a[16];
  int k0 = (int)toks[gt];
  const float* e0 = Ef32 + (size_t)k0 * 256 + q * 64;
  #pragma unroll
  for (int i = 0; i < 16; ++i) a[i] = ((const float4*)e0)[i];
  #pragma unroll
  for (int v = 1; v < V_; ++v) {
    int kv = (int)toks[v * TOKSZ + gt];
    const float* ev = Ef32 + (size_t)v * DK_ + (size_t)kv * 256 + q * 64;
    #pragma unroll
    for (int i = 0; i < 16; ++i) {
      float4 e = ((const float4*)ev)[i];
      a[i].x += e.x; a[i].y += e.y; a[i].z += e.z; a[i].w += e.w;
    }
  }
  float* dst = out + (size_t)b * DN_ + n;
  #pragma unroll
  for (int i = 0; i < 16; ++i) {
    int d = q * 64 + i * 4;
    dst[(size_t)(d + 0) * N_] = a[i].x;
    dst[(size_t)(d + 1) * N_] = a[i].y;
    dst[(size_t)(d + 2) * N_] = a[i].z;
    dst[(size_t)(d + 3) * N_] = a[i].w;
  }
}

__global__ __launch_bounds__(256) void loss_kernel(const float* __restrict__ part,
                                                   float* __restrict__ out) {
  __shared__ float s[256];
  const int tid = threadIdx.x;
  float a = 0.f;
  for (int i = tid; i < V_ * NBLK; i += 256) a += part[i];
  s[tid] = a;
  __syncthreads();
  for (int st = 128; st >= 1; st >>= 1) {
    if (tid < st) s[tid] += s[tid + st];
    __syncthreads();
  }
  if (tid == 0) out[LOSS_OFF] = s[0] * (1.0f / (float)QSZ);
}

extern "C" void kernel_launch(void* const* d_in, const int* in_sizes, int n_in,
                              void* d_out, int out_size, void* d_ws, size_t ws_size,
                              hipStream_t stream) {
  (void)in_sizes; (void)n_in; (void)out_size; (void)ws_size;
  const float* inputs = (const float*)d_in[0];
  const float* emb    = (const float*)d_in[1];
  float* out = (float*)d_out;
  char* ws = (char*)d_ws;

  unsigned short* Ehi = (unsigned short*)(ws + 0);          // 1572864 B
  unsigned short* Elo = (unsigned short*)(ws + 1572864);    // 1572864 B
  float*  Ef32 = (float*)(ws + 3145728);                    // 3145728 B
  float*  en2f = (float*)(ws + 6291456);                    // 12288 B
  double* en2d = (double*)(ws + 6303744);                   // 24576 B
  float*  part = (float*)(ws + 6328320);                    // 49152 B (V*NBLK)
  int*    flagCnt  = (int*)(ws + 6377472);                  // 4 B
  int*    flagList = (int*)(ws + 6377476);                  // 131072 B

  float* toks = out + TOK_OFF;

  hipMemsetAsync(flagCnt, 0, sizeof(int), stream);
  pack_kernel<<<dim3(8, 4, 6), 256, 0, stream>>>(emb, Ef32, Ehi, Elo);
  en2_kernel<<<48, 256, 0, stream>>>(Ef32, en2f, en2d);
  rvq_fused<<<NBLK, 256, 0, stream>>>(inputs, Ehi, Elo, Ef32, en2f,
                                      toks, part, flagCnt, flagList);
  chain_fixup<<<2048, 256, 0, stream>>>(inputs, Ef32, en2d, toks, flagList, flagCnt);
  finalize_q<<<TOKSZ / 64, 256, 0, stream>>>(toks, Ef32, out);
  loss_kernel<<<1, 256, 0, stream>>>(part, out);
}

// Round 11
// 766.521 us; speedup vs baseline: 1.4505x; 1.4505x over previous
//
#include <hip/hip_runtime.h>
#include <cfloat>

#define B_  32
#define D_  256
#define N_  2048
#define K_  512
#define V_  6
#define DN_ (D_*N_)        // 524288
#define DK_ (D_*K_)        // 131072
#define QSZ (B_*D_*N_)     // 16777216
#define TOKSZ (B_*N_)      // 65536
#define TOK_OFF QSZ
#define LOSS_OFF (QSZ + V_*TOKSZ)
#define MARGIN 0.02f
#define FCAP 32768
#define TPB 128                  // tokens per block
#define NBLK (TOKSZ/TPB)         // 512 blocks

typedef __attribute__((ext_vector_type(8))) short short8b;   // 8 bf16 (4 VGPR)
typedef __attribute__((ext_vector_type(4))) float f32x4;

__device__ __forceinline__ unsigned short f2bf(float x) {
  unsigned u = __float_as_uint(x);
  unsigned r = (u + 0x7fffu + ((u >> 16) & 1u)) >> 16;   // RNE
  return (unsigned short)r;
}
__device__ __forceinline__ float bf2f(unsigned short h) {
  return __uint_as_float(((unsigned)h) << 16);
}
__device__ __forceinline__ unsigned orderf(float f) {   // total order as unsigned
  unsigned u = __float_as_uint(f);
  return (u >> 31) ? ~u : (u | 0x80000000u);
}
__device__ __forceinline__ float unorderf(unsigned u) {
  return __uint_as_float((u & 0x80000000u) ? (u & 0x7fffffffu) : ~u);
}
__device__ __forceinline__ unsigned long long shfl_xor_u64(unsigned long long v, int m) {
  int lo = __shfl_xor((int)(unsigned)(v & 0xffffffffull), m, 64);
  int hi = __shfl_xor((int)(unsigned)(v >> 32), m, 64);
  return ((unsigned long long)(unsigned)hi << 32) | (unsigned)lo;
}

// ---- prep: transpose emb[v][d][k] -> Ef32[vk][d] + bf16 hi/lo packs ----
__global__ __launch_bounds__(256) void pack_kernel(const float* __restrict__ emb,
                                                   float* __restrict__ Ef32,
                                                   unsigned short* __restrict__ Ehi,
                                                   unsigned short* __restrict__ Elo) {
  __shared__ float T[64][68];
  const int tid = threadIdx.x;
  const int k0 = blockIdx.x * 64, d0 = blockIdx.y * 64, v = blockIdx.z;
  const float* src = emb + (size_t)v * DK_;
  const int r = tid >> 4, c4 = (tid & 15) * 4;
  #pragma unroll
  for (int i = 0; i < 4; ++i) {
    int d = d0 + r + i * 16;
    float4 x = *(const float4*)(src + (size_t)d * K_ + k0 + c4);
    *(float4*)&T[r + i * 16][c4] = x;
  }
  __syncthreads();
  #pragma unroll
  for (int i = 0; i < 4; ++i) {
    int k = k0 + r + i * 16;
    float4 wv;
    wv.x = T[c4 + 0][r + i * 16];
    wv.y = T[c4 + 1][r + i * 16];
    wv.z = T[c4 + 2][r + i * 16];
    wv.w = T[c4 + 3][r + i * 16];
    size_t o = ((size_t)v * K_ + k) * 256 + d0 + c4;
    *(float4*)(Ef32 + o) = wv;
    ushort4 hv, lv;
    hv.x = f2bf(wv.x); lv.x = f2bf(wv.x - bf2f(hv.x));
    hv.y = f2bf(wv.y); lv.y = f2bf(wv.y - bf2f(hv.y));
    hv.z = f2bf(wv.z); lv.z = f2bf(wv.z - bf2f(hv.z));
    hv.w = f2bf(wv.w); lv.w = f2bf(wv.w - bf2f(hv.w));
    *(ushort4*)(Ehi + o) = hv;
    *(ushort4*)(Elo + o) = lv;
  }
}

// ---- ||e||^2 in f32 and f64 ----
__global__ __launch_bounds__(256) void en2_kernel(const float* __restrict__ Ef32,
                                                  float* __restrict__ en2f,
                                                  double* __restrict__ en2d) {
  __shared__ double P[64][4];
  const int tid = threadIdx.x;
  const int k = blockIdx.x * 64 + (tid >> 2), q = tid & 3;
  const float* e = Ef32 + (size_t)k * 256 + q * 64;
  double s = 0.0;
  #pragma unroll 8
  for (int i = 0; i < 64; ++i) { double x = (double)e[i]; s = fma(x, x, s); }
  P[tid >> 2][q] = s;
  __syncthreads();
  if (tid < 64) {
    int k2 = blockIdx.x * 64 + tid;
    double t = (P[tid][0] + P[tid][1]) + (P[tid][2] + P[tid][3]);
    en2d[k2] = t;
    en2f[k2] = (float)t;
  }
}

// ---- fused all-6-layer RVQ: 128 tokens/block, 8 waves, wave = 128tok x 64k.
// acc[8][4]=128 AGPR + ~100 VGPR ~ 230 <= 256 budget -> 8 waves/CU, no spill.
// All loops fully unrolled (rule #20: runtime acc index -> scratch).
__global__ __launch_bounds__(512) void rvq_fused(
    const float* __restrict__ inputs,
    const unsigned short* __restrict__ Ehi, const unsigned short* __restrict__ Elo,
    const float* __restrict__ Ef32, const float* __restrict__ en2f,
    float* __restrict__ tokens, float* __restrict__ lossPart,
    int* __restrict__ flagCnt, int* __restrict__ flagList)
{
  __shared__ unsigned short Ahi[8 * 4 * TPB * 8];   // 64 KB  [c][g][tok][8]
  __shared__ unsigned short Alo[8 * 4 * TPB * 8];   // 64 KB
  __shared__ unsigned long long wmin[8][TPB];       // 8 KB
  __shared__ float wsec[8][TPB];                    // 4 KB
  __shared__ int sIdx[TPB];                         // 0.5 KB
  __shared__ float wred[8];

  const int tid = threadIdx.x;
  const int lane = tid & 63, w = tid >> 6;          // 8 waves
  const int l15 = lane & 15, lg = lane >> 4;
  const int gt0 = blockIdx.x * TPB;
  const int b = gt0 >> 11, n0 = gt0 & (N_ - 1);
  const int kb = w * 64;                            // 64 codes per wave

  // ---- stage inputs once: tok = tid&127, cq = tid>>7 handles c=cq and cq+4
  {
    const int tok = tid & (TPB - 1), cq = tid >> 7;
    const float* src = inputs + (size_t)b * DN_ + n0 + tok;
    #pragma unroll
    for (int cc = 0; cc < 2; ++cc) {
      const int c = cq + cc * 4;
      #pragma unroll
      for (int g = 0; g < 4; ++g) {
        short8b hv, lv;
        #pragma unroll
        for (int e = 0; e < 8; ++e) {
          float x = src[(size_t)(c * 32 + g * 8 + e) * N_];
          unsigned short h = f2bf(x);
          hv[e] = (short)h;
          lv[e] = (short)f2bf(x - bf2f(h));
        }
        *(short8b*)&Ahi[((c * 4 + g) * TPB + tok) * 8] = hv;
        *(short8b*)&Alo[((c * 4 + g) * TPB + tok) * 8] = lv;
      }
    }
  }
  __syncthreads();

  for (int v = 0; v < V_; ++v) {
    const unsigned short* ehiL = Ehi + (size_t)v * DK_ + (size_t)(kb + l15) * 256 + lg * 8;
    const unsigned short* eloL = Elo + (size_t)v * DK_ + (size_t)(kb + l15) * 256 + lg * 8;
    const float* Ef32v = Ef32 + (size_t)v * DK_;

    f32x4 acc[8][4];
    #pragma unroll
    for (int tt = 0; tt < 8; ++tt)
      #pragma unroll
      for (int kt = 0; kt < 4; ++kt) acc[tt][kt] = (f32x4){0.f, 0.f, 0.f, 0.f};

    // ---- barrier-free bf16x3 MFMA: 8 d-chunks, B reused across 8 token-tiles
    #pragma unroll
    for (int c = 0; c < 8; ++c) {
      short8b ah[8], al[8];
      #pragma unroll
      for (int tt = 0; tt < 8; ++tt) {
        ah[tt] = *(const short8b*)&Ahi[((c * 4 + lg) * TPB + tt * 16 + l15) * 8];
        al[tt] = *(const short8b*)&Alo[((c * 4 + lg) * TPB + tt * 16 + l15) * 8];
      }
      #pragma unroll
      for (int kt = 0; kt < 4; ++kt) {
        short8b bh = *(const short8b*)(ehiL + (size_t)kt * 4096 + c * 32);
        short8b bl = *(const short8b*)(eloL + (size_t)kt * 4096 + c * 32);
        #pragma unroll
        for (int tt = 0; tt < 8; ++tt) {
          acc[tt][kt] = __builtin_amdgcn_mfma_f32_16x16x32_bf16(ah[tt], bh, acc[tt][kt], 0, 0, 0);
          acc[tt][kt] = __builtin_amdgcn_mfma_f32_16x16x32_bf16(ah[tt], bl, acc[tt][kt], 0, 0, 0);
          acc[tt][kt] = __builtin_amdgcn_mfma_f32_16x16x32_bf16(al[tt], bh, acc[tt][kt], 0, 0, 0);
        }
      }
    }

    float en4[4];
    #pragma unroll
    for (int kt = 0; kt < 4; ++kt) en4[kt] = en2f[v * K_ + kb + kt * 16 + l15];

    // ---- argmin + second-best per token (first-index tie-break)
    #pragma unroll
    for (int tt = 0; tt < 8; ++tt)
      #pragma unroll
      for (int r = 0; r < 4; ++r) {
        const int token = tt * 16 + lg * 4 + r;
        float dv0 = en4[0] - 2.f * acc[tt][0][r];
        unsigned long long p = ((unsigned long long)orderf(dv0) << 32) | (unsigned)(kb + l15);
        float s = FLT_MAX;
        #pragma unroll
        for (int kt = 1; kt < 4; ++kt) {
          float dv = en4[kt] - 2.f * acc[tt][kt][r];
          unsigned long long pk = ((unsigned long long)orderf(dv) << 32) |
                                  (unsigned)(kb + kt * 16 + l15);
          if (pk < p) { s = fminf(s, unorderf((unsigned)(p >> 32))); p = pk; }
          else s = fminf(s, dv);
        }
        #pragma unroll
        for (int m = 1; m <= 8; m <<= 1) {
          unsigned long long po = shfl_xor_u64(p, m);
          float so = __shfl_xor(s, m, 64);
          unsigned long long pmax = (po < p) ? p : po;
          s = fminf(fminf(s, so), unorderf((unsigned)(pmax >> 32)));
          p = (po < p) ? po : p;
        }
        if (l15 == 0) { wmin[w][token] = p; wsec[w][token] = s; }
      }
    __syncthreads();
    if (tid < TPB) {
      unsigned long long p = wmin[0][tid]; float s = wsec[0][tid];
      #pragma unroll
      for (int w2 = 1; w2 < 8; ++w2) {
        unsigned long long po = wmin[w2][tid]; float so = wsec[w2][tid];
        unsigned long long pmax = (po < p) ? p : po;
        s = fminf(fminf(s, so), unorderf((unsigned)(pmax >> 32)));
        p = (po < p) ? po : p;
      }
      int kwin = (int)(p & 0xffffffffull);
      sIdx[tid] = kwin;
      tokens[(size_t)v * TOKSZ + gt0 + tid] = (float)kwin;
      float bd = unorderf((unsigned)(p >> 32));
      if (s - bd < MARGIN) {          // near-tie: defer to exact post-pass
        int pos = atomicAdd(flagCnt, 1);
        if (pos < FCAP) flagList[pos] = gt0 + tid;
      }
    }
    __syncthreads();

    // ---- residual update in LDS: rn = (hi+lo) - e, re-split; fused loss
    // uj = tid&127 (token), cq = tid>>7 -> c-chunks cq*2, cq*2+1 (64 d/thread).
    // Same-(cq) threads hit consecutive 16B LDS slots -> conflict-free.
    const int uj = tid & (TPB - 1), cq = tid >> 7;
    const int kw = sIdx[uj];
    float lacc = 0.f;
    #pragma unroll
    for (int cc = 0; cc < 2; ++cc) {
      const int c = cq * 2 + cc;
      const float* er = Ef32v + (size_t)kw * 256 + c * 32;
      #pragma unroll
      for (int g = 0; g < 4; ++g) {
        unsigned short* ph = &Ahi[((c * 4 + g) * TPB + uj) * 8];
        unsigned short* pl = &Alo[((c * 4 + g) * TPB + uj) * 8];
        short8b h8 = *(const short8b*)ph;
        short8b l8 = *(const short8b*)pl;
        float4 e0 = *(const float4*)(er + g * 8);
        float4 e1 = *(const float4*)(er + g * 8 + 4);
        float ee[8] = {e0.x, e0.y, e0.z, e0.w, e1.x, e1.y, e1.z, e1.w};
        short8b nh, nl;
        #pragma unroll
        for (int jj = 0; jj < 8; ++jj) {
          float rv = bf2f((unsigned short)h8[jj]) + bf2f((unsigned short)l8[jj]);
          float rn = rv - ee[jj];
          unsigned short hh = f2bf(rn);
          nh[jj] = (short)hh;
          nl[jj] = (short)f2bf(rn - bf2f(hh));
          lacc += rn * rn;
        }
        if (v < V_ - 1) {
          *(short8b*)ph = nh;
          *(short8b*)pl = nl;
        }
      }
    }
    #pragma unroll
    for (int m = 32; m >= 1; m >>= 1) lacc += __shfl_xor(lacc, m, 64);
    if (lane == 0) wred[w] = lacc;
    __syncthreads();
    if (tid == 0) {
      float t = 0.f;
      #pragma unroll
      for (int w2 = 0; w2 < 8; ++w2) t += wred[w2];
      lossPart[(size_t)v * NBLK + blockIdx.x] = t;
    }
    __syncthreads();   // Ahi/Alo + wred stable before next layer
  }
}

// ---- exact f64 full-chain re-argmin for flagged tokens (post-pass) ----
__global__ __launch_bounds__(256) void chain_fixup(
    const float* __restrict__ inputs, const float* __restrict__ Ef32,
    const double* __restrict__ en2d, float* __restrict__ tokens,
    const int* __restrict__ flagList, const int* __restrict__ flagCnt)
{
  __shared__ double rD[256];
  __shared__ double sbd[256];
  __shared__ int sbk[256];
  const int tid = threadIdx.x;
  int cnt = flagCnt[0]; if (cnt > FCAP) cnt = FCAP;
  for (int i = blockIdx.x; i < cnt; i += gridDim.x) {
    const int gt = flagList[i];
    const int b = gt >> 11, n = gt & (N_ - 1);
    rD[tid] = (double)inputs[(size_t)b * DN_ + (size_t)tid * N_ + n];
    __syncthreads();
    for (int v = 0; v < V_; ++v) {
      const float* Ev = Ef32 + (size_t)v * DK_;
      double best = 1.0e300; int bk = 0;
      #pragma unroll
      for (int half = 0; half < 2; ++half) {
        const int k = tid + half * 256;
        const float* e0 = Ev + (size_t)k * 256;
        double s0 = 0.0, s1 = 0.0, s2 = 0.0, s3 = 0.0;
        #pragma unroll 8
        for (int dd = 0; dd < 256; dd += 4) {
          s0 = fma(rD[dd + 0], (double)e0[dd + 0], s0);
          s1 = fma(rD[dd + 1], (double)e0[dd + 1], s1);
          s2 = fma(rD[dd + 2], (double)e0[dd + 2], s2);
          s3 = fma(rD[dd + 3], (double)e0[dd + 3], s3);
        }
        double dist = en2d[v * K_ + k] - 2.0 * ((s0 + s1) + (s2 + s3));
        if (dist < best) { best = dist; bk = k; }   // k=tid before tid+256: keep lower
      }
      sbd[tid] = best; sbk[tid] = bk;
      __syncthreads();
      for (int st = 128; st >= 1; st >>= 1) {
        if (tid < st) {
          double od = sbd[tid + st]; int ok = sbk[tid + st];
          if (od < sbd[tid] || (od == sbd[tid] && ok < sbk[tid])) {
            sbd[tid] = od; sbk[tid] = ok;
          }
        }
        __syncthreads();
      }
      const int nk = sbk[0];
      if (tid == 0) tokens[(size_t)v * TOKSZ + gt] = (float)nk;
      double e = (double)Ev[(size_t)nk * 256 + tid];
      __syncthreads();
      rD[tid] = rD[tid] - e;
      __syncthreads();
    }
  }
}

// ---- q_sum[b][d][n] = sum_v Ef32[v][tok_v][d] ----
__global__ __launch_bounds__(256) void finalize_q(const float* __restrict__ toks,
                                                  const float* __restrict__ Ef32,
                                                  float* __restrict__ out) {
  const int tid = threadIdx.x;
  const int gt = blockIdx.x * 64 + (tid >> 2);
  const int q = tid & 3;
  const int b = gt >> 11, n = gt & (N_ - 1);
  float4 a[16];
  int k0 = (int)toks[gt];
  const float* e0 = Ef32 + (size_t)k0 * 256 + q * 64;
  #pragma unroll
  for (int i = 0; i < 16; ++i) a[i] = ((const float4*)e0)[i];
  #pragma unroll
  for (int v = 1; v < V_; ++v) {
    int kv = (int)toks[v * TOKSZ + gt];
    const float* ev = Ef32 + (size_t)v * DK_ + (size_t)kv * 256 + q * 64;
    #pragma unroll
    for (int i = 0; i < 16; ++i) {
      float4 e = ((const float4*)ev)[i];
      a[i].x += e.x; a[i].y += e.y; a[i].z += e.z; a[i].w += e.w;
    }
  }
  float* dst = out + (size_t)b * DN_ + n;
  #pragma unroll
  for (int i = 0; i < 16; ++i) {
    int d = q * 64 + i * 4;
    dst[(size_t)(d + 0) * N_] = a[i].x;
    dst[(size_t)(d + 1) * N_] = a[i].y;
    dst[(size_t)(d + 2) * N_] = a[i].z;
    dst[(size_t)(d + 3) * N_] = a[i].w;
  }
}

__global__ __launch_bounds__(256) void loss_kernel(const float* __restrict__ part,
                                                   float* __restrict__ out) {
  __shared__ float s[256];
  const int tid = threadIdx.x;
  float a = 0.f;
  for (int i = tid; i < V_ * NBLK; i += 256) a += part[i];
  s[tid] = a;
  __syncthreads();
  for (int st = 128; st >= 1; st >>= 1) {
    if (tid < st) s[tid] += s[tid + st];
    __syncthreads();
  }
  if (tid == 0) out[LOSS_OFF] = s[0] * (1.0f / (float)QSZ);
}

extern "C" void kernel_launch(void* const* d_in, const int* in_sizes, int n_in,
                              void* d_out, int out_size, void* d_ws, size_t ws_size,
                              hipStream_t stream) {
  (void)in_sizes; (void)n_in; (void)out_size; (void)ws_size;
  const float* inputs = (const float*)d_in[0];
  const float* emb    = (const float*)d_in[1];
  float* out = (float*)d_out;
  char* ws = (char*)d_ws;

  unsigned short* Ehi = (unsigned short*)(ws + 0);          // 1572864 B
  unsigned short* Elo = (unsigned short*)(ws + 1572864);    // 1572864 B
  float*  Ef32 = (float*)(ws + 3145728);                    // 3145728 B
  float*  en2f = (float*)(ws + 6291456);                    // 12288 B
  double* en2d = (double*)(ws + 6303744);                   // 24576 B
  float*  part = (float*)(ws + 6328320);                    // 12288 B (V*NBLK)
  int*    flagCnt  = (int*)(ws + 6340608);                  // 4 B
  int*    flagList = (int*)(ws + 6340612);                  // 131072 B

  float* toks = out + TOK_OFF;

  hipMemsetAsync(flagCnt, 0, sizeof(int), stream);
  pack_kernel<<<dim3(8, 4, 6), 256, 0, stream>>>(emb, Ef32, Ehi, Elo);
  en2_kernel<<<48, 256, 0, stream>>>(Ef32, en2f, en2d);
  rvq_fused<<<NBLK, 512, 0, stream>>>(inputs, Ehi, Elo, Ef32, en2f,
                                      toks, part, flagCnt, flagList);
  chain_fixup<<<2048, 256, 0, stream>>>(inputs, Ef32, en2d, toks, flagList, flagCnt);
  finalize_q<<<TOKSZ / 64, 256, 0, stream>>>(toks, Ef32, out);
  loss_kernel<<<1, 256, 0, stream>>>(part, out);
}

// Round 12
// 732.114 us; speedup vs baseline: 1.5187x; 1.0470x over previous
//
#include <hip/hip_runtime.h>
#include <cfloat>

#define B_  32
#define D_  256
#define N_  2048
#define K_  512
#define V_  6
#define DN_ (D_*N_)        // 524288
#define DK_ (D_*K_)        // 131072
#define QSZ (B_*D_*N_)     // 16777216
#define TOKSZ (B_*N_)      // 65536
#define TOK_OFF QSZ
#define LOSS_OFF (QSZ + V_*TOKSZ)
#define MARGIN 0.02f
#define FCAP 32768
#define TPB 128                  // tokens per block
#define NBLK (TOKSZ/TPB)         // 512 blocks

typedef __attribute__((ext_vector_type(8))) short short8b;   // 8 bf16 (4 VGPR)
typedef __attribute__((ext_vector_type(4))) float f32x4;

__device__ __forceinline__ unsigned short f2bf(float x) {
  unsigned u = __float_as_uint(x);
  unsigned r = (u + 0x7fffu + ((u >> 16) & 1u)) >> 16;   // RNE
  return (unsigned short)r;
}
__device__ __forceinline__ float bf2f(unsigned short h) {
  return __uint_as_float(((unsigned)h) << 16);
}
__device__ __forceinline__ unsigned orderf(float f) {   // total order as unsigned
  unsigned u = __float_as_uint(f);
  return (u >> 31) ? ~u : (u | 0x80000000u);
}
__device__ __forceinline__ float unorderf(unsigned u) {
  return __uint_as_float((u & 0x80000000u) ? (u & 0x7fffffffu) : ~u);
}
__device__ __forceinline__ unsigned long long shfl_xor_u64(unsigned long long v, int m) {
  int lo = __shfl_xor((int)(unsigned)(v & 0xffffffffull), m, 64);
  int hi = __shfl_xor((int)(unsigned)(v >> 32), m, 64);
  return ((unsigned long long)(unsigned)hi << 32) | (unsigned)lo;
}

// ---- prep: transpose emb[v][d][k] -> Ef32[vk][d] + bf16 hi/lo packs ----
__global__ __launch_bounds__(256) void pack_kernel(const float* __restrict__ emb,
                                                   float* __restrict__ Ef32,
                                                   unsigned short* __restrict__ Ehi,
                                                   unsigned short* __restrict__ Elo) {
  __shared__ float T[64][68];
  const int tid = threadIdx.x;
  const int k0 = blockIdx.x * 64, d0 = blockIdx.y * 64, v = blockIdx.z;
  const float* src = emb + (size_t)v * DK_;
  const int r = tid >> 4, c4 = (tid & 15) * 4;
  #pragma unroll
  for (int i = 0; i < 4; ++i) {
    int d = d0 + r + i * 16;
    float4 x = *(const float4*)(src + (size_t)d * K_ + k0 + c4);
    *(float4*)&T[r + i * 16][c4] = x;
  }
  __syncthreads();
  #pragma unroll
  for (int i = 0; i < 4; ++i) {
    int k = k0 + r + i * 16;
    float4 wv;
    wv.x = T[c4 + 0][r + i * 16];
    wv.y = T[c4 + 1][r + i * 16];
    wv.z = T[c4 + 2][r + i * 16];
    wv.w = T[c4 + 3][r + i * 16];
    size_t o = ((size_t)v * K_ + k) * 256 + d0 + c4;
    *(float4*)(Ef32 + o) = wv;
    ushort4 hv, lv;
    hv.x = f2bf(wv.x); lv.x = f2bf(wv.x - bf2f(hv.x));
    hv.y = f2bf(wv.y); lv.y = f2bf(wv.y - bf2f(hv.y));
    hv.z = f2bf(wv.z); lv.z = f2bf(wv.z - bf2f(hv.z));
    hv.w = f2bf(wv.w); lv.w = f2bf(wv.w - bf2f(hv.w));
    *(ushort4*)(Ehi + o) = hv;
    *(ushort4*)(Elo + o) = lv;
  }
}

// ---- ||e||^2 in f32 and f64 ----
__global__ __launch_bounds__(256) void en2_kernel(const float* __restrict__ Ef32,
                                                  float* __restrict__ en2f,
                                                  double* __restrict__ en2d) {
  __shared__ double P[64][4];
  const int tid = threadIdx.x;
  const int k = blockIdx.x * 64 + (tid >> 2), q = tid & 3;
  const float* e = Ef32 + (size_t)k * 256 + q * 64;
  double s = 0.0;
  #pragma unroll 8
  for (int i = 0; i < 64; ++i) { double x = (double)e[i]; s = fma(x, x, s); }
  P[tid >> 2][q] = s;
  __syncthreads();
  if (tid < 64) {
    int k2 = blockIdx.x * 64 + tid;
    double t = (P[tid][0] + P[tid][1]) + (P[tid][2] + P[tid][3]);
    en2d[k2] = t;
    en2f[k2] = (float)t;
  }
}

// ---- fused all-6-layer RVQ: 128 tokens/block, 8 waves, wave = 128tok x 64k.
// MFMA phase: B-fragments (8 named regs, 32 VGPR) outer, A streamed per-tt
// (2 live frags) -> peak live ~40 VGPR + 128 AGPR acc: no spill (round-11
// held 16 A-frags live -> 328 MB scratch writes). All loops fully unrolled
// (rule #20: runtime acc index -> scratch). 2 barriers/layer.
__global__ __launch_bounds__(512) void rvq_fused(
    const float* __restrict__ inputs,
    const unsigned short* __restrict__ Ehi, const unsigned short* __restrict__ Elo,
    const float* __restrict__ Ef32, const float* __restrict__ en2f,
    float* __restrict__ tokens, float* __restrict__ lossPart,
    int* __restrict__ flagCnt, int* __restrict__ flagList)
{
  __shared__ unsigned short Ahi[8 * 4 * TPB * 8];   // 64 KB  [c][g][tok][8]
  __shared__ unsigned short Alo[8 * 4 * TPB * 8];   // 64 KB
  __shared__ unsigned long long wmin[8][TPB];       // 8 KB
  __shared__ float wsec[8][TPB];                    // 4 KB

  const int tid = threadIdx.x;
  const int lane = tid & 63, w = tid >> 6;          // 8 waves
  const int l15 = lane & 15, lg = lane >> 4;
  const int gt0 = blockIdx.x * TPB;
  const int b = gt0 >> 11, n0 = gt0 & (N_ - 1);
  const int kb = w * 64;                            // 64 codes per wave

  // ---- stage inputs once: tok = tid&127, cq = tid>>7 handles c=cq and cq+4
  {
    const int tok = tid & (TPB - 1), cq = tid >> 7;
    const float* src = inputs + (size_t)b * DN_ + n0 + tok;
    #pragma unroll
    for (int cc = 0; cc < 2; ++cc) {
      const int c = cq + cc * 4;
      #pragma unroll
      for (int g = 0; g < 4; ++g) {
        short8b hv, lv;
        #pragma unroll
        for (int e = 0; e < 8; ++e) {
          float x = src[(size_t)(c * 32 + g * 8 + e) * N_];
          unsigned short h = f2bf(x);
          hv[e] = (short)h;
          lv[e] = (short)f2bf(x - bf2f(h));
        }
        *(short8b*)&Ahi[((c * 4 + g) * TPB + tok) * 8] = hv;
        *(short8b*)&Alo[((c * 4 + g) * TPB + tok) * 8] = lv;
      }
    }
  }
  __syncthreads();

  for (int v = 0; v < V_; ++v) {
    const unsigned short* ehiL = Ehi + (size_t)v * DK_ + (size_t)(kb + l15) * 256 + lg * 8;
    const unsigned short* eloL = Elo + (size_t)v * DK_ + (size_t)(kb + l15) * 256 + lg * 8;
    const float* Ef32v = Ef32 + (size_t)v * DK_;

    f32x4 acc[8][4];
    #pragma unroll
    for (int tt = 0; tt < 8; ++tt)
      #pragma unroll
      for (int kt = 0; kt < 4; ++kt) acc[tt][kt] = (f32x4){0.f, 0.f, 0.f, 0.f};

    // ---- barrier-free bf16x3 MFMA: B (8 named regs) outer, A streamed
    #pragma unroll
    for (int c = 0; c < 8; ++c) {
      const unsigned short* bph = ehiL + c * 32;
      const unsigned short* bpl = eloL + c * 32;
      short8b bh0 = *(const short8b*)(bph);
      short8b bh1 = *(const short8b*)(bph + 4096);
      short8b bh2 = *(const short8b*)(bph + 8192);
      short8b bh3 = *(const short8b*)(bph + 12288);
      short8b bl0 = *(const short8b*)(bpl);
      short8b bl1 = *(const short8b*)(bpl + 4096);
      short8b bl2 = *(const short8b*)(bpl + 8192);
      short8b bl3 = *(const short8b*)(bpl + 12288);
      #pragma unroll
      for (int tt = 0; tt < 8; ++tt) {
        short8b ah = *(const short8b*)&Ahi[((c * 4 + lg) * TPB + tt * 16 + l15) * 8];
        short8b al = *(const short8b*)&Alo[((c * 4 + lg) * TPB + tt * 16 + l15) * 8];
        acc[tt][0] = __builtin_amdgcn_mfma_f32_16x16x32_bf16(ah, bh0, acc[tt][0], 0, 0, 0);
        acc[tt][0] = __builtin_amdgcn_mfma_f32_16x16x32_bf16(ah, bl0, acc[tt][0], 0, 0, 0);
        acc[tt][0] = __builtin_amdgcn_mfma_f32_16x16x32_bf16(al, bh0, acc[tt][0], 0, 0, 0);
        acc[tt][1] = __builtin_amdgcn_mfma_f32_16x16x32_bf16(ah, bh1, acc[tt][1], 0, 0, 0);
        acc[tt][1] = __builtin_amdgcn_mfma_f32_16x16x32_bf16(ah, bl1, acc[tt][1], 0, 0, 0);
        acc[tt][1] = __builtin_amdgcn_mfma_f32_16x16x32_bf16(al, bh1, acc[tt][1], 0, 0, 0);
        acc[tt][2] = __builtin_amdgcn_mfma_f32_16x16x32_bf16(ah, bh2, acc[tt][2], 0, 0, 0);
        acc[tt][2] = __builtin_amdgcn_mfma_f32_16x16x32_bf16(ah, bl2, acc[tt][2], 0, 0, 0);
        acc[tt][2] = __builtin_amdgcn_mfma_f32_16x16x32_bf16(al, bh2, acc[tt][2], 0, 0, 0);
        acc[tt][3] = __builtin_amdgcn_mfma_f32_16x16x32_bf16(ah, bh3, acc[tt][3], 0, 0, 0);
        acc[tt][3] = __builtin_amdgcn_mfma_f32_16x16x32_bf16(ah, bl3, acc[tt][3], 0, 0, 0);
        acc[tt][3] = __builtin_amdgcn_mfma_f32_16x16x32_bf16(al, bh3, acc[tt][3], 0, 0, 0);
      }
    }

    float en4[4];
    #pragma unroll
    for (int kt = 0; kt < 4; ++kt) en4[kt] = en2f[v * K_ + kb + kt * 16 + l15];

    // ---- per-wave argmin + second-best per token (first-index tie-break)
    #pragma unroll
    for (int tt = 0; tt < 8; ++tt)
      #pragma unroll
      for (int r = 0; r < 4; ++r) {
        const int token = tt * 16 + lg * 4 + r;
        float dv0 = en4[0] - 2.f * acc[tt][0][r];
        unsigned long long p = ((unsigned long long)orderf(dv0) << 32) | (unsigned)(kb + l15);
        float s = FLT_MAX;
        #pragma unroll
        for (int kt = 1; kt < 4; ++kt) {
          float dv = en4[kt] - 2.f * acc[tt][kt][r];
          unsigned long long pk = ((unsigned long long)orderf(dv) << 32) |
                                  (unsigned)(kb + kt * 16 + l15);
          if (pk < p) { s = fminf(s, unorderf((unsigned)(p >> 32))); p = pk; }
          else s = fminf(s, dv);
        }
        #pragma unroll
        for (int m = 1; m <= 8; m <<= 1) {
          unsigned long long po = shfl_xor_u64(p, m);
          float so = __shfl_xor(s, m, 64);
          unsigned long long pmax = (po < p) ? p : po;
          s = fminf(fminf(s, so), unorderf((unsigned)(pmax >> 32)));
          p = (po < p) ? po : p;
        }
        if (l15 == 0) { wmin[w][token] = p; wsec[w][token] = s; }
      }
    __syncthreads();

    // ---- cross-wave argmin: ALL threads reduce their own token (broadcast
    // LDS reads, 4x redundant) -> no idle section, no extra barrier
    const int uj = tid & (TPB - 1), cq = tid >> 7;
    unsigned long long p = wmin[0][uj]; float s = wsec[0][uj];
    #pragma unroll
    for (int w2 = 1; w2 < 8; ++w2) {
      unsigned long long po = wmin[w2][uj]; float so = wsec[w2][uj];
      unsigned long long pmax = (po < p) ? p : po;
      s = fminf(fminf(s, so), unorderf((unsigned)(pmax >> 32)));
      p = (po < p) ? po : p;
    }
    const int kw = (int)(p & 0xffffffffull);
    if (tid < TPB) {
      tokens[(size_t)v * TOKSZ + gt0 + tid] = (float)kw;
      float bd = unorderf((unsigned)(p >> 32));
      if (s - bd < MARGIN) {          // near-tie: defer to exact post-pass
        int pos = atomicAdd(flagCnt, 1);
        if (pos < FCAP) flagList[pos] = gt0 + tid;
      }
    }

    // ---- residual update in LDS: rn = (hi+lo) - e, re-split; fused loss
    float lacc = 0.f;
    #pragma unroll
    for (int cc = 0; cc < 2; ++cc) {
      const int c = cq * 2 + cc;
      const float* er = Ef32v + (size_t)kw * 256 + c * 32;
      #pragma unroll
      for (int g = 0; g < 4; ++g) {
        unsigned short* ph = &Ahi[((c * 4 + g) * TPB + uj) * 8];
        unsigned short* pl = &Alo[((c * 4 + g) * TPB + uj) * 8];
        short8b h8 = *(const short8b*)ph;
        short8b l8 = *(const short8b*)pl;
        float4 e0 = *(const float4*)(er + g * 8);
        float4 e1 = *(const float4*)(er + g * 8 + 4);
        float ee[8] = {e0.x, e0.y, e0.z, e0.w, e1.x, e1.y, e1.z, e1.w};
        short8b nh, nl;
        #pragma unroll
        for (int jj = 0; jj < 8; ++jj) {
          float rv = bf2f((unsigned short)h8[jj]) + bf2f((unsigned short)l8[jj]);
          float rn = rv - ee[jj];
          unsigned short hh = f2bf(rn);
          nh[jj] = (short)hh;
          nl[jj] = (short)f2bf(rn - bf2f(hh));
          lacc += rn * rn;
        }
        if (v < V_ - 1) {
          *(short8b*)ph = nh;
          *(short8b*)pl = nl;
        }
      }
    }
    #pragma unroll
    for (int m = 32; m >= 1; m >>= 1) lacc += __shfl_xor(lacc, m, 64);
    if (lane == 0)
      lossPart[((size_t)v * NBLK + blockIdx.x) * 8 + w] = lacc;
    __syncthreads();   // Ahi/Alo update visible before next layer's MFMA
  }
}

// ---- exact f64 full-chain re-argmin for flagged tokens (post-pass) ----
__global__ __launch_bounds__(256) void chain_fixup(
    const float* __restrict__ inputs, const float* __restrict__ Ef32,
    const double* __restrict__ en2d, float* __restrict__ tokens,
    const int* __restrict__ flagList, const int* __restrict__ flagCnt)
{
  __shared__ double rD[256];
  __shared__ double sbd[256];
  __shared__ int sbk[256];
  const int tid = threadIdx.x;
  int cnt = flagCnt[0]; if (cnt > FCAP) cnt = FCAP;
  for (int i = blockIdx.x; i < cnt; i += gridDim.x) {
    const int gt = flagList[i];
    const int b = gt >> 11, n = gt & (N_ - 1);
    rD[tid] = (double)inputs[(size_t)b * DN_ + (size_t)tid * N_ + n];
    __syncthreads();
    for (int v = 0; v < V_; ++v) {
      const float* Ev = Ef32 + (size_t)v * DK_;
      double best = 1.0e300; int bk = 0;
      #pragma unroll
      for (int half = 0; half < 2; ++half) {
        const int k = tid + half * 256;
        const float* e0 = Ev + (size_t)k * 256;
        double s0 = 0.0, s1 = 0.0, s2 = 0.0, s3 = 0.0;
        #pragma unroll 8
        for (int dd = 0; dd < 256; dd += 4) {
          s0 = fma(rD[dd + 0], (double)e0[dd + 0], s0);
          s1 = fma(rD[dd + 1], (double)e0[dd + 1], s1);
          s2 = fma(rD[dd + 2], (double)e0[dd + 2], s2);
          s3 = fma(rD[dd + 3], (double)e0[dd + 3], s3);
        }
        double dist = en2d[v * K_ + k] - 2.0 * ((s0 + s1) + (s2 + s3));
        if (dist < best) { best = dist; bk = k; }   // k=tid before tid+256: keep lower
      }
      sbd[tid] = best; sbk[tid] = bk;
      __syncthreads();
      for (int st = 128; st >= 1; st >>= 1) {
        if (tid < st) {
          double od = sbd[tid + st]; int ok = sbk[tid + st];
          if (od < sbd[tid] || (od == sbd[tid] && ok < sbk[tid])) {
            sbd[tid] = od; sbk[tid] = ok;
          }
        }
        __syncthreads();
      }
      const int nk = sbk[0];
      if (tid == 0) tokens[(size_t)v * TOKSZ + gt] = (float)nk;
      double e = (double)Ev[(size_t)nk * 256 + tid];
      __syncthreads();
      rD[tid] = rD[tid] - e;
      __syncthreads();
    }
  }
}

// ---- q_sum[b][d][n] = sum_v Ef32[v][tok_v][d] ----
__global__ __launch_bounds__(256) void finalize_q(const float* __restrict__ toks,
                                                  const float* __restrict__ Ef32,
                                                  float* __restrict__ out) {
  const int tid = threadIdx.x;
  const int gt = blockIdx.x * 64 + (tid >> 2);
  const int q = tid & 3;
  const int b = gt >> 11, n = gt & (N_ - 1);
  float4 a[16];
  int k0 = (int)toks[gt];
  const float* e0 = Ef32 + (size_t)k0 * 256 + q * 64;
  #pragma unroll
  for (int i = 0; i < 16; ++i) a[i] = ((const float4*)e0)[i];
  #pragma unroll
  for (int v = 1; v < V_; ++v) {
    int kv = (int)toks[v * TOKSZ + gt];
    const float* ev = Ef32 + (size_t)v * DK_ + (size_t)kv * 256 + q * 64;
    #pragma unroll
    for (int i = 0; i < 16; ++i) {
      float4 e = ((const float4*)ev)[i];
      a[i].x += e.x; a[i].y += e.y; a[i].z += e.z; a[i].w += e.w;
    }
  }
  float* dst = out + (size_t)b * DN_ + n;
  #pragma unroll
  for (int i = 0; i < 16; ++i) {
    int d = q * 64 + i * 4;
    dst[(size_t)(d + 0) * N_] = a[i].x;
    dst[(size_t)(d + 1) * N_] = a[i].y;
    dst[(size_t)(d + 2) * N_] = a[i].z;
    dst[(size_t)(d + 3) * N_] = a[i].w;
  }
}

__global__ __launch_bounds__(256) void loss_kernel(const float* __restrict__ part,
                                                   float* __restrict__ out) {
  __shared__ float s[256];
  const int tid = threadIdx.x;
  float a = 0.f;
  for (int i = tid; i < V_ * NBLK * 8; i += 256) a += part[i];
  s[tid] = a;
  __syncthreads();
  for (int st = 128; st >= 1; st >>= 1) {
    if (tid < st) s[tid] += s[tid + st];
    __syncthreads();
  }
  if (tid == 0) out[LOSS_OFF] = s[0] * (1.0f / (float)QSZ);
}

extern "C" void kernel_launch(void* const* d_in, const int* in_sizes, int n_in,
                              void* d_out, int out_size, void* d_ws, size_t ws_size,
                              hipStream_t stream) {
  (void)in_sizes; (void)n_in; (void)out_size; (void)ws_size;
  const float* inputs = (const float*)d_in[0];
  const float* emb    = (const float*)d_in[1];
  float* out = (float*)d_out;
  char* ws = (char*)d_ws;

  unsigned short* Ehi = (unsigned short*)(ws + 0);          // 1572864 B
  unsigned short* Elo = (unsigned short*)(ws + 1572864);    // 1572864 B
  float*  Ef32 = (float*)(ws + 3145728);                    // 3145728 B
  float*  en2f = (float*)(ws + 6291456);                    // 12288 B
  double* en2d = (double*)(ws + 6303744);                   // 24576 B
  float*  part = (float*)(ws + 6328320);                    // 98304 B (V*NBLK*8)
  int*    flagCnt  = (int*)(ws + 6426624);                  // 4 B
  int*    flagList = (int*)(ws + 6426628);                  // 131072 B

  float* toks = out + TOK_OFF;

  hipMemsetAsync(flagCnt, 0, sizeof(int), stream);
  pack_kernel<<<dim3(8, 4, 6), 256, 0, stream>>>(emb, Ef32, Ehi, Elo);
  en2_kernel<<<48, 256, 0, stream>>>(Ef32, en2f, en2d);
  rvq_fused<<<NBLK, 512, 0, stream>>>(inputs, Ehi, Elo, Ef32, en2f,
                                      toks, part, flagCnt, flagList);
  chain_fixup<<<2048, 256, 0, stream>>>(inputs, Ef32, en2d, toks, flagList, flagCnt);
  finalize_q<<<TOKSZ / 64, 256, 0, stream>>>(toks, Ef32, out);
  loss_kernel<<<1, 256, 0, stream>>>(part, out);
}